// Round 1
// baseline (576.266 us; speedup 1.0000x reference)
//
#include <hip/hip_runtime.h>
#include <hip/hip_bf16.h>
#include <cstdint>
#include <cfloat>

#define BATCH   4096
#define IN_DIM  1024
#define D_MODEL 1024
#define BRANCH  16
#define HEIGHT  4
#define N_NODES 69904   // 16 + 256 + 4096 + 65536

// ---------------------------------------------------------------------------
// fp32 GEMM: C[M,N] = A[M,K] * B[K,N].  BM=BN=64, BK=16, 256 thr, 4x4/thread.
// No fp32 MFMA on CDNA4 -> vector ALU. Keep fp32 for argmax fidelity.
// ---------------------------------------------------------------------------
__global__ __launch_bounds__(256) void gemm_f32(const float* __restrict__ A,
                                                const float* __restrict__ B,
                                                float* __restrict__ C,
                                                int M, int N, int K) {
    __shared__ float As[16][68];   // As[k][m], +4 pad keeps 16B align, breaks pow2
    __shared__ float Bs[16][68];   // Bs[k][n]

    const int t  = threadIdx.x;
    const int tx = t & 15;         // 16 cols of threads
    const int ty = t >> 4;         // 16 rows of threads
    const int bm = blockIdx.x;     // M / 64
    const int bn = blockIdx.y;     // N / 64

    const int arow = t >> 2;             // 0..63
    const int ac4  = (t & 3) * 4;        // 0,4,8,12
    const int brow = t >> 4;             // 0..15
    const int bc4  = (t & 15) * 4;       // 0..60

    const float* Ab = A + (size_t)(bm * 64) * K;
    const float* Bb = B + (size_t)bn * 64;

    float acc[4][4] = {};

    for (int k0 = 0; k0 < K; k0 += 16) {
        float4 av = *(const float4*)(Ab + (size_t)arow * K + k0 + ac4);
        float4 bv = *(const float4*)(Bb + (size_t)(k0 + brow) * N + bc4);

        As[ac4 + 0][arow] = av.x;
        As[ac4 + 1][arow] = av.y;
        As[ac4 + 2][arow] = av.z;
        As[ac4 + 3][arow] = av.w;
        *(float4*)&Bs[brow][bc4] = bv;
        __syncthreads();

#pragma unroll
        for (int k = 0; k < 16; ++k) {
            float4 a = *(const float4*)&As[k][ty * 4];
            float4 b = *(const float4*)&Bs[k][tx * 4];
            const float aa[4] = {a.x, a.y, a.z, a.w};
            const float bb[4] = {b.x, b.y, b.z, b.w};
#pragma unroll
            for (int i = 0; i < 4; ++i)
#pragma unroll
                for (int j = 0; j < 4; ++j)
                    acc[i][j] = fmaf(aa[i], bb[j], acc[i][j]);
        }
        __syncthreads();
    }

    float* Cb = C + (size_t)(bm * 64 + ty * 4) * N + bn * 64 + tx * 4;
#pragma unroll
    for (int i = 0; i < 4; ++i) {
        float4 v = {acc[i][0], acc[i][1], acc[i][2], acc[i][3]};
        *(float4*)(Cb + (size_t)i * N) = v;
    }
}

// ---------------------------------------------------------------------------
// Tree descent: one wave per batch row. Lane = (g, k), g = lane>>4 in [0,4)
// is a d-phase, k = lane&15 is the candidate slot. Children of a node are
// CONTIGUOUS ids, so Xi[d, base..base+15] is a contiguous 64B chunk ->
// each wave load instr = 4 x 64B coalesced segments.
// ---------------------------------------------------------------------------
__global__ __launch_bounds__(256) void descend(const float* __restrict__ f,
                                               const float* __restrict__ Xi,
                                               const int* __restrict__ children,
                                               int* __restrict__ out) {
    __shared__ float fs[4][1024];

    const int lane = threadIdx.x & 63;
    const int w    = threadIdx.x >> 6;
    const int b    = blockIdx.x * 4 + w;

    // Stage this row of f into LDS (float4 coalesced).
    {
        const float4* frow = (const float4*)(f + (size_t)b * D_MODEL);
        float4* fsw = (float4*)fs[w];
#pragma unroll
        for (int i = 0; i < 4; ++i) fsw[lane + 64 * i] = frow[lane + 64 * i];
    }
    __syncthreads();

    const int g = lane >> 4;   // d-phase 0..3  (d = 4*t + g -> 4 distinct banks)
    const int k = lane & 15;   // candidate slot

    int cur = 0;
    if (lane == 0) out[(size_t)b * (HEIGHT + 1)] = 0;

    for (int lev = 0; lev < HEIGHT; ++lev) {
        const int child = children[(size_t)cur * BRANCH + k];
        const int valid = child > 0;
        const int col   = valid ? child - 1 : 0;

        const float* xp = Xi + (size_t)g * N_NODES + col;
        const float* fr = fs[w] + g;
        const size_t step = (size_t)4 * N_NODES;

        float acc = 0.f;
#pragma unroll 16
        for (int t = 0; t < 256; ++t) {
            acc = fmaf(fr[4 * t], *xp, acc);
            xp += step;
        }

        // sum the 4 d-phases: lanes k, k+16, k+32, k+48 hold partials of g_k
        acc += __shfl_xor(acc, 16);
        acc += __shfl_xor(acc, 32);
        if (!valid) acc = -FLT_MAX;

        // argmax over the 16 candidate slots (butterfly within 16-lane groups);
        // tie-break toward smaller k to match jnp.argmax first-max semantics.
        float bv = acc;
        int   bk = k;
        int   bc = child;
#pragma unroll
        for (int m = 1; m < 16; m <<= 1) {
            float ov = __shfl_xor(bv, m);
            int   ok = __shfl_xor(bk, m);
            int   oc = __shfl_xor(bc, m);
            if (ov > bv || (ov == bv && ok < bk)) { bv = ov; bk = ok; bc = oc; }
        }

        const int any = (bv > -FLT_MAX) ? 1 : 0;
        const int nxt = any ? bc : 0;
        if (lane == 0) out[(size_t)b * (HEIGHT + 1) + lev + 1] = nxt;
        cur = any ? nxt : cur;
    }
}

// ---------------------------------------------------------------------------
extern "C" void kernel_launch(void* const* d_in, const int* in_sizes, int n_in,
                              void* d_out, int out_size, void* d_ws, size_t ws_size,
                              hipStream_t stream) {
    const float* X        = (const float*)d_in[0];   // [BATCH, IN_DIM]
    const float* W        = (const float*)d_in[1];   // [IN_DIM, D_MODEL]
    const float* Xi       = (const float*)d_in[2];   // [D_MODEL, N_NODES]
    const int*   children = (const int*)d_in[3];     // [N_NODES+1, BRANCH]
    int* out = (int*)d_out;                          // [BATCH, HEIGHT+1] int32

    float* f = (float*)d_ws;                         // [BATCH, D_MODEL] scratch

    dim3 ggrid(BATCH / 64, D_MODEL / 64);
    gemm_f32<<<ggrid, 256, 0, stream>>>(X, W, f, BATCH, D_MODEL, IN_DIM);

    descend<<<BATCH / 4, 256, 0, stream>>>(f, Xi, children, out);
}